// Round 3
// baseline (6173.257 us; speedup 1.0000x reference)
//
#include <hip/hip_runtime.h>
#include <hip/hip_bf16.h>
#include <stdint.h>

#define B_    64
#define T_    512
#define H_    512
#define G_    2048    // 4*H
#define TAGS_ 20

typedef __hip_bfloat16 bf16;
typedef __bf16 bf16x8 __attribute__((ext_vector_type(8)));
typedef float  f32x4  __attribute__((ext_vector_type(4)));

__device__ __forceinline__ float sigmoidf_(float x) { return 1.0f / (1.0f + __expf(-x)); }

// ---------------- prep kernels ----------------

__global__ void k_zero(uint32_t* __restrict__ p, int n) {
    for (int i = blockIdx.x * blockDim.x + threadIdx.x; i < n; i += gridDim.x * blockDim.x)
        p[i] = 0u;
}

__global__ void k_f2b(const float* __restrict__ s, bf16* __restrict__ d, int n) {
    for (int i = blockIdx.x * blockDim.x + threadIdx.x; i < n; i += gridDim.x * blockDim.x)
        d[i] = __float2bfloat16(s[i]);
}

__global__ void k_addb(const float* __restrict__ a, const float* __restrict__ b,
                       float* __restrict__ o, int n) {
    for (int i = blockIdx.x * blockDim.x + threadIdx.x; i < n; i += gridDim.x * blockDim.x)
        o[i] = a[i] + b[i];
}

__global__ __launch_bounds__(256) void k_lens(const int* __restrict__ x, int* __restrict__ lens) {
    int b = blockIdx.x;
    int cnt = 0;
    for (int tpos = threadIdx.x; tpos < T_; tpos += 256)
        cnt += (x[(size_t)b * T_ + tpos] == 0) ? 1 : 0;
    #pragma unroll
    for (int off = 32; off; off >>= 1) cnt += __shfl_xor(cnt, off);
    __shared__ int tot;
    if (threadIdx.x == 0) tot = 0;
    __syncthreads();
    if ((threadIdx.x & 63) == 0) atomicAdd(&tot, cnt);
    __syncthreads();
    if (threadIdx.x == 0) lens[b] = T_ - tot;
}

// E[t][b][d] = bf16(emb[x[b][t]][d])
__global__ void k_gather(const int* __restrict__ x, const float* __restrict__ emb,
                         bf16* __restrict__ E) {
    int t = blockIdx.x, b = blockIdx.y;
    int tok = x[(size_t)b * T_ + t];
    const float* src = emb + (size_t)tok * H_;
    bf16* dst = E + ((size_t)t * B_ + b) * H_;
    for (int d = threadIdx.x; d < H_; d += blockDim.x)
        dst[d] = __float2bfloat16(src[d]);
}

// ---------------- persistent 2-layer LSTM ----------------
// 256 blocks x 256 threads. block = (layer, mtile, strip); wave = gate.
// Weights PINNED register-resident (32 f32x4-as-bf16x8 frags/wave, asm keep-alive).
// x-part computed before the own-group sync (off the serialized path).
__global__ __launch_bounds__(256, 1) void k_lstm(
    const bf16* __restrict__ E,
    const bf16* __restrict__ W0x, const bf16* __restrict__ W0h, const float* __restrict__ bias0,
    const bf16* __restrict__ W1x, const bf16* __restrict__ W1h, const float* __restrict__ bias1,
    bf16* __restrict__ h0ring, bf16* __restrict__ h1ring,
    float* __restrict__ last1, const int* __restrict__ lens,
    int* __restrict__ counters)
{
    const int bid   = blockIdx.x;
    const int layer = bid >> 7;          // 0..1
    const int m     = (bid >> 5) & 3;    // batch tile (16 rows)
    const int s     = bid & 31;          // hidden strip (16 cols)
    const int tid   = threadIdx.x;
    const int lane  = tid & 63;
    const int q     = tid >> 6;          // wave = gate
    const int l15   = lane & 15;
    const int kq    = (lane >> 4) * 8;

    // ---- load this wave's weights into registers (pinned across steps) ----
    const bf16* Wx = layer ? W1x : W0x;
    const bf16* Wh = layer ? W1h : W0h;
    const int jc = s * 16 + l15;                       // hidden col in [0,512)
    f32x4 w[32];
    #pragma unroll
    for (int kc = 0; kc < 16; ++kc)
        w[kc] = *reinterpret_cast<const f32x4*>(Wx + ((size_t)(q * H_ + jc)) * H_ + kc * 32 + kq);
    #pragma unroll
    for (int kc = 0; kc < 16; ++kc)
        w[16 + kc] = *reinterpret_cast<const f32x4*>(Wh + ((size_t)(q * H_ + jc)) * H_ + kc * 32 + kq);

    __shared__ float glds[4][16][20];   // [gate][j][row(+pad)]

    // ---- elementwise thread mapping: one (b,j) per thread, c in register ----
    const int eb   = tid >> 4;          // local batch row 0..15
    const int ej   = tid & 15;          // local col 0..15
    const int brow = m * 16 + eb;
    const int jcol = s * 16 + ej;
    float c_reg = 0.f;
    const float* bias = layer ? bias1 : bias0;
    const float bi0 = bias[0 * H_ + jcol];
    const float bi1 = bias[1 * H_ + jcol];
    const float bi2 = bias[2 * H_ + jcol];
    const float bi3 = bias[3 * H_ + jcol];
    int target = lens[brow] - 1;
    if (target < 0) target = T_ - 1;    // python -1 wrap

    int* ctr_own   = counters + (layer * 4 + m) * 32;
    int* ctr_other = counters + ((1 - layer) * 4 + m) * 32;

    const int arow = m * 16 + l15;      // A-fragment row
    bf16* myring = layer ? h1ring : h0ring;

    for (int tt = 0; tt < T_; ++tt) {
        // keep-alive: force all 32 weight fragments to stay in VGPRs
        #pragma unroll
        for (int i = 0; i < 32; ++i)
            asm volatile("" : "+v"(w[i]));

        // ---- phase A: x-part (no own-group dependency) ----
        if (layer == 1) {
            if (tid == 0) {
                while (__hip_atomic_load(ctr_other, __ATOMIC_RELAXED, __HIP_MEMORY_SCOPE_AGENT) < 32 * (tt + 1))
                    __builtin_amdgcn_s_sleep(1);
                __builtin_amdgcn_fence(__ATOMIC_ACQUIRE, "agent");
            }
            __syncthreads();
        }
        const bf16* xsrc = layer ? (h0ring + (size_t)(tt & 7) * (B_ * H_))
                                 : (E + (size_t)tt * (B_ * H_));
        const bf16* xp = xsrc + (size_t)arow * H_ + kq;

        f32x4 acc[4];
        #pragma unroll
        for (int i = 0; i < 4; ++i) acc[i] = f32x4{0.f, 0.f, 0.f, 0.f};
        #pragma unroll
        for (int kc = 0; kc < 16; ++kc) {
            f32x4 A = *reinterpret_cast<const f32x4*>(xp + kc * 32);
            acc[kc & 3] = __builtin_amdgcn_mfma_f32_16x16x32_bf16(
                __builtin_bit_cast(bf16x8, A), __builtin_bit_cast(bf16x8, w[kc]), acc[kc & 3], 0, 0, 0);
        }

        // ---- phase B: own-group sync, then h-part ----
        if (tid == 0) {
            while (__hip_atomic_load(ctr_own, __ATOMIC_RELAXED, __HIP_MEMORY_SCOPE_AGENT) < 32 * tt)
                __builtin_amdgcn_s_sleep(1);
            if (layer == 0) {   // ring flow control: l1 must have consumed slot tt-8
                while (__hip_atomic_load(ctr_other, __ATOMIC_RELAXED, __HIP_MEMORY_SCOPE_AGENT) < 32 * (tt - 7))
                    __builtin_amdgcn_s_sleep(1);
            }
            __builtin_amdgcn_fence(__ATOMIC_ACQUIRE, "agent");
        }
        __syncthreads();

        const bf16* hsrc = myring + (size_t)((tt - 1) & 7) * (B_ * H_);
        const bf16* hp = hsrc + (size_t)arow * H_ + kq;
        #pragma unroll
        for (int kc = 0; kc < 16; ++kc) {
            f32x4 A = *reinterpret_cast<const f32x4*>(hp + kc * 32);
            acc[kc & 3] = __builtin_amdgcn_mfma_f32_16x16x32_bf16(
                __builtin_bit_cast(bf16x8, A), __builtin_bit_cast(bf16x8, w[16 + kc]), acc[kc & 3], 0, 0, 0);
        }
        f32x4 g = (acc[0] + acc[1]) + (acc[2] + acc[3]);

        // ---- gate exchange via LDS: wave q writes its 16x16 tile ----
        const int rb = (lane >> 4) * 4;
        *reinterpret_cast<f32x4*>(&glds[q][l15][rb]) = g;
        __syncthreads();

        // ---- elementwise LSTM update ----
        float gi = sigmoidf_(glds[0][ej][eb] + bi0);
        float gf = sigmoidf_(glds[1][ej][eb] + bi1);
        float gg = tanhf   (glds[2][ej][eb] + bi2);
        float go = sigmoidf_(glds[3][ej][eb] + bi3);
        c_reg = gf * c_reg + gi * gg;
        float hn = go * tanhf(c_reg);
        myring[(size_t)(tt & 7) * (B_ * H_) + (size_t)brow * H_ + jcol] = __float2bfloat16(hn);
        if (layer == 1 && tt == target)
            last1[(size_t)brow * H_ + jcol] = hn;
        __syncthreads();

        // ---- publish step completion ----
        if (tid == 0) {
            __builtin_amdgcn_fence(__ATOMIC_RELEASE, "agent");
            __hip_atomic_fetch_add(ctr_own, 1, __ATOMIC_RELAXED, __HIP_MEMORY_SCOPE_AGENT);
        }
    }
}

// out[b][tag] = last1[b] . Wout[tag] + bout[tag]   (fp32)
__global__ __launch_bounds__(64) void k_out(const float* __restrict__ last1,
                                            const float* __restrict__ Wout,
                                            const float* __restrict__ bout,
                                            float* __restrict__ out) {
    int b = blockIdx.x, tg = blockIdx.y, lane = threadIdx.x;
    float sum = 0.f;
    for (int d = lane; d < H_; d += 64)
        sum += last1[(size_t)b * H_ + d] * Wout[(size_t)tg * H_ + d];
    #pragma unroll
    for (int off = 32; off; off >>= 1) sum += __shfl_xor(sum, off);
    if (lane == 0) out[b * TAGS_ + tg] = sum + bout[tg];
}

// ---------------- host ----------------

extern "C" void kernel_launch(void* const* d_in, const int* in_sizes, int n_in,
                              void* d_out, int out_size, void* d_ws, size_t ws_size,
                              hipStream_t stream)
{
    const int*   x    = (const int*)  d_in[0];
    const float* emb  = (const float*)d_in[1];
    const float* Wih0 = (const float*)d_in[2];
    const float* Whh0 = (const float*)d_in[3];
    const float* bih0 = (const float*)d_in[4];
    const float* bhh0 = (const float*)d_in[5];
    const float* Wih1 = (const float*)d_in[6];
    const float* Whh1 = (const float*)d_in[7];
    const float* bih1 = (const float*)d_in[8];
    const float* bhh1 = (const float*)d_in[9];
    const float* Wout = (const float*)d_in[10];
    const float* bout = (const float*)d_in[11];
    float* out = (float*)d_out;

    char* p = (char*)d_ws;
    bf16* E    = (bf16*)p;  p += (size_t)T_ * B_ * H_ * 2;      // 32 MB
    bf16* W0x  = (bf16*)p;  p += (size_t)G_ * H_ * 2;
    bf16* W0h  = (bf16*)p;  p += (size_t)G_ * H_ * 2;
    bf16* W1x  = (bf16*)p;  p += (size_t)G_ * H_ * 2;
    bf16* W1h  = (bf16*)p;  p += (size_t)G_ * H_ * 2;
    float* bias0 = (float*)p; p += (size_t)G_ * 4;
    float* bias1 = (float*)p; p += (size_t)G_ * 4;
    char* zbase = p;                                            // zeroed every launch
    bf16* h0ring = (bf16*)p; p += (size_t)8 * B_ * H_ * 2;      // 512 KB
    bf16* h1ring = (bf16*)p; p += (size_t)8 * B_ * H_ * 2;      // 512 KB
    int*  counters = (int*)p; p += 8 * 32 * 4;                  // 8 group counters, 128B apart
    size_t zbytes = (size_t)(p - zbase);
    float* last1 = (float*)p; p += (size_t)B_ * H_ * 4;
    int* lens = (int*)p; p += 256;

    k_zero<<<dim3(128), dim3(256), 0, stream>>>((uint32_t*)zbase, (int)(zbytes / 4));
    k_lens<<<dim3(B_), dim3(256), 0, stream>>>(x, lens);
    k_f2b<<<dim3(512), dim3(256), 0, stream>>>(Wih0, W0x, G_ * H_);
    k_f2b<<<dim3(512), dim3(256), 0, stream>>>(Whh0, W0h, G_ * H_);
    k_f2b<<<dim3(512), dim3(256), 0, stream>>>(Wih1, W1x, G_ * H_);
    k_f2b<<<dim3(512), dim3(256), 0, stream>>>(Whh1, W1h, G_ * H_);
    k_addb<<<dim3(8), dim3(256), 0, stream>>>(bih0, bhh0, bias0, G_);
    k_addb<<<dim3(8), dim3(256), 0, stream>>>(bih1, bhh1, bias1, G_);
    k_gather<<<dim3(T_, B_), dim3(256), 0, stream>>>(x, emb, E);

    k_lstm<<<dim3(256), dim3(256), 0, stream>>>(E, W0x, W0h, bias0, W1x, W1h, bias1,
                                                h0ring, h1ring, last1, lens, counters);

    k_out<<<dim3(B_, TAGS_), dim3(64), 0, stream>>>(last1, Wout, bout, out);
}

// Round 4
// 3301.923 us; speedup vs baseline: 1.8696x; 1.8696x over previous
//
#include <hip/hip_runtime.h>
#include <hip/hip_bf16.h>
#include <stdint.h>

#define B_    64
#define T_    512
#define H_    512
#define G_    2048    // 4*H
#define TAGS_ 20

typedef __hip_bfloat16 bf16;
typedef __bf16 bf16x8 __attribute__((ext_vector_type(8)));
typedef float  f32x4  __attribute__((ext_vector_type(4)));

__device__ __forceinline__ float sigmoidf_(float x) { return 1.0f / (1.0f + __expf(-x)); }

// ---------------- prep kernels ----------------

__global__ void k_zero(uint32_t* __restrict__ p, int n) {
    for (int i = blockIdx.x * blockDim.x + threadIdx.x; i < n; i += gridDim.x * blockDim.x)
        p[i] = 0u;
}

__global__ void k_addb(const float* __restrict__ a, const float* __restrict__ b,
                       float* __restrict__ o, int n) {
    for (int i = blockIdx.x * blockDim.x + threadIdx.x; i < n; i += gridDim.x * blockDim.x)
        o[i] = a[i] + b[i];
}

__global__ __launch_bounds__(256) void k_lens(const int* __restrict__ x, int* __restrict__ lens) {
    int b = blockIdx.x;
    int cnt = 0;
    for (int tpos = threadIdx.x; tpos < T_; tpos += 256)
        cnt += (x[(size_t)b * T_ + tpos] == 0) ? 1 : 0;
    #pragma unroll
    for (int off = 32; off; off >>= 1) cnt += __shfl_xor(cnt, off);
    __shared__ int tot;
    if (threadIdx.x == 0) tot = 0;
    __syncthreads();
    if ((threadIdx.x & 63) == 0) atomicAdd(&tot, cnt);
    __syncthreads();
    if (threadIdx.x == 0) lens[b] = T_ - tot;
}

// E[t][b][d] = bf16(emb[x[b][t]][d])
__global__ void k_gather(const int* __restrict__ x, const float* __restrict__ emb,
                         bf16* __restrict__ E) {
    int t = blockIdx.x, b = blockIdx.y;
    int tok = x[(size_t)b * T_ + t];
    const float* src = emb + (size_t)tok * H_;
    bf16* dst = E + ((size_t)t * B_ + b) * H_;
    for (int d = threadIdx.x; d < H_; d += blockDim.x)
        dst[d] = __float2bfloat16(src[d]);
}

// Pack weights into fragment-linear order (fused fp32->bf16):
// Wp[(l*32+s)*65536 + ((q*32+kc)*64+lane)*8 .. +8]
//   kc<16 -> W_ih chunk kc ; kc>=16 -> W_hh chunk kc-16
//   row = q*512 + s*16 + (lane&15); col = (kc&15)*32 + (lane>>4)*8
__global__ __launch_bounds__(256) void k_pack(const float* __restrict__ Wih0, const float* __restrict__ Whh0,
                                              const float* __restrict__ Wih1, const float* __restrict__ Whh1,
                                              bf16* __restrict__ Wp) {
    const int s = blockIdx.x, q = blockIdx.y, l = blockIdx.z;
    const float* Wx = l ? Wih1 : Wih0;
    const float* Wh = l ? Whh1 : Whh0;
    bf16* base = Wp + (size_t)(l * 32 + s) * 65536;
    for (int u = threadIdx.x; u < 2048; u += 256) {
        int kc = u >> 6, lane = u & 63;
        int row = q * H_ + s * 16 + (lane & 15);
        int col = (kc & 15) * 32 + (lane >> 4) * 8;
        const float* src = ((kc < 16) ? Wx : Wh) + (size_t)row * H_ + col;
        bf16* dst = base + ((size_t)(q * 32 + kc) * 64 + lane) * 8;
        #pragma unroll
        for (int e = 0; e < 8; ++e) dst[e] = __float2bfloat16(src[e]);
    }
}

// ---------------- coherent (L3-scope) helpers ----------------

__device__ __forceinline__ void wave_poll(const int* fa, int ta, const int* fb, int tb, int lane) {
    if (ta <= 0 && tb <= 0) return;
    const int* p = (lane < 32) ? (fa + lane) : (fb + (lane - 32));
    int thr = (lane < 32) ? ta : tb;
    int guard = 0;
    while (true) {
        int v;
        asm volatile("global_load_dword %0, %1, off sc0 sc1\n\t"
                     "s_waitcnt vmcnt(0)"
                     : "=v"(v) : "v"(p) : "memory");
        if (__all(v >= thr)) break;
        if (++guard > (1 << 22)) break;   // safety: no infinite hang
        __builtin_amdgcn_s_sleep(1);
    }
    __builtin_amdgcn_sched_barrier(0);
}

#define ISSUE16(arr, base, SC)                                               \
    _Pragma("unroll")                                                        \
    for (int kc = 0; kc < 16; ++kc) {                                        \
        asm volatile("global_load_dwordx4 %0, %1, off" SC                    \
                     : "=v"(arr[kc]) : "v"((base) + kc * 32));               \
    }

#define WAITALL()                                                            \
    asm volatile("s_waitcnt vmcnt(0)" ::: "memory");                         \
    __builtin_amdgcn_sched_barrier(0);

#define MFMA16(arr, woff)                                                    \
    _Pragma("unroll")                                                        \
    for (int kc = 0; kc < 16; ++kc) {                                        \
        f32x4 wf = wldsv[(size_t)(q * 32 + (woff) + kc) * 64 + lane];        \
        acc[kc & 3] = __builtin_amdgcn_mfma_f32_16x16x32_bf16(               \
            __builtin_bit_cast(bf16x8, arr[kc]),                             \
            __builtin_bit_cast(bf16x8, wf), acc[kc & 3], 0, 0, 0);           \
    }

// ---------------- persistent 2-layer LSTM ----------------
// 256 blocks (1/CU, 133KB dyn LDS). block = (g = layer*4+m  [bid&7], strip s [bid>>3]).
// Weights in LDS (fragment-linear, conflict-free ds_read_b128). c in registers.
// Cross-block: sc0/sc1 coherent loads/stores + per-strip flags; NO cache-wide fences.
__global__ __launch_bounds__(256, 1) void k_lstm(
    const bf16* __restrict__ Wp, const bf16* __restrict__ E,
    const float* __restrict__ bias0, const float* __restrict__ bias1,
    bf16* __restrict__ h0ring, bf16* __restrict__ h1ring,
    int* __restrict__ flags, float* __restrict__ last1, const int* __restrict__ lens)
{
    extern __shared__ char smem[];                       // [0,128K) weights, [128K,+5K) gates
    f32x4* wldsv = (f32x4*)smem;
    float (*glds)[16][20] = (float (*)[16][20])(smem + 131072);

    const int bid   = blockIdx.x;
    const int g     = bid & 7;           // group: layer*4+m (XCD-local by empirical bid%8)
    const int s     = bid >> 3;          // strip 0..31
    const int layer = g >> 2;
    const int m     = g & 3;
    const int tid   = threadIdx.x;
    const int lane  = tid & 63;
    const int q     = tid >> 6;          // wave = gate
    const int kq    = (lane >> 4) * 8;
    const int arow  = m * 16 + (lane & 15);

    // ---- stage this block's 128KB weight slice into LDS ----
    {
        const f32x4* wsrc = (const f32x4*)(Wp + (size_t)(layer * 32 + s) * 65536);
        for (int i = tid; i < 8192; i += 256) wldsv[i] = wsrc[i];
    }

    // ---- elementwise mapping: one (b,j) per thread, c in register ----
    const int eb   = tid >> 4;
    const int ej   = tid & 15;
    const int brow = m * 16 + eb;
    const int jcol = s * 16 + ej;
    float c_reg = 0.f;
    const float* bias = layer ? bias1 : bias0;
    const float bi0 = bias[0 * H_ + jcol];
    const float bi1 = bias[1 * H_ + jcol];
    const float bi2 = bias[2 * H_ + jcol];
    const float bi3 = bias[3 * H_ + jcol];
    int target = lens[brow] - 1;
    if (target < 0) target = T_ - 1;

    int* fown = flags + g * 32;
    int* foth = flags + (g ^ 4) * 32;    // other layer, same m
    bf16* myring = layer ? h1ring : h0ring;

    __syncthreads();                     // weights staged

    for (int tt = 0; tt < T_; ++tt) {
        f32x4 acc[4];
        #pragma unroll
        for (int i = 0; i < 4; ++i) acc[i] = f32x4{0.f, 0.f, 0.f, 0.f};
        f32x4 a[16];

        if (layer == 0) {
            // x-part from E: no cross-block dependency
            const bf16* xp = E + ((size_t)tt * B_ + arow) * H_ + kq;
            ISSUE16(a, xp, "")
            WAITALL()
            MFMA16(a, 0)
            // wait: own group done step tt-1; l1 consumed ring slot (>= tt-7)
            wave_poll(fown, tt, foth, tt - 7, lane);
            const bf16* hp = h0ring + (size_t)((tt - 1) & 7) * (B_ * H_) + (size_t)arow * H_ + kq;
            ISSUE16(a, hp, " sc0 sc1")
            WAITALL()
            MFMA16(a, 16)
        } else {
            // own h-part first (off the l0->l1 chain)
            wave_poll(fown, tt, fown, -1, lane);
            const bf16* hp = h1ring + (size_t)((tt - 1) & 7) * (B_ * H_) + (size_t)arow * H_ + kq;
            ISSUE16(a, hp, " sc0 sc1")
            WAITALL()
            MFMA16(a, 16)
            // now wait for l0 step tt, then x-part from h0
            wave_poll(foth, tt + 1, foth, -1, lane);
            const bf16* xp = h0ring + (size_t)(tt & 7) * (B_ * H_) + (size_t)arow * H_ + kq;
            ISSUE16(a, xp, " sc0 sc1")
            WAITALL()
            MFMA16(a, 0)
        }

        f32x4 gsum = (acc[0] + acc[1]) + (acc[2] + acc[3]);

        // ---- gate exchange via LDS ----
        const int rb = (lane >> 4) * 4;
        *reinterpret_cast<f32x4*>(&glds[q][lane & 15][rb]) = gsum;
        __syncthreads();

        // ---- elementwise LSTM update ----
        float gi = sigmoidf_(glds[0][ej][eb] + bi0);
        float gf = sigmoidf_(glds[1][ej][eb] + bi1);
        float gg = tanhf   (glds[2][ej][eb] + bi2);
        float go = sigmoidf_(glds[3][ej][eb] + bi3);
        c_reg = gf * c_reg + gi * gg;
        float hn = go * tanhf(c_reg);

        {   // coherent 2B store of h
            bf16 hb = __float2bfloat16(hn);
            uint32_t hv = (uint32_t)__builtin_bit_cast(unsigned short, hb);
            bf16* hw = myring + (size_t)(tt & 7) * (B_ * H_) + (size_t)brow * H_ + jcol;
            asm volatile("global_store_short %0, %1, off sc0 sc1" :: "v"(hw), "v"(hv) : "memory");
        }
        if (layer == 1 && tt == target)
            last1[(size_t)brow * H_ + jcol] = hn;

        asm volatile("s_waitcnt vmcnt(0)" ::: "memory");   // h visible at L3
        __syncthreads();                                   // all threads drained

        if (tid == 0) {
            int* fp = fown + s;
            int fv = tt + 1;
            asm volatile("global_store_dword %0, %1, off sc0 sc1" :: "v"(fp), "v"(fv) : "memory");
        }
        __syncthreads();   // keep glds stable until next write
    }
}

// out[b][tag] = last1[b] . Wout[tag] + bout[tag]   (fp32)
__global__ __launch_bounds__(64) void k_out(const float* __restrict__ last1,
                                            const float* __restrict__ Wout,
                                            const float* __restrict__ bout,
                                            float* __restrict__ out) {
    int b = blockIdx.x, tg = blockIdx.y, lane = threadIdx.x;
    float sum = 0.f;
    for (int d = lane; d < H_; d += 64)
        sum += last1[(size_t)b * H_ + d] * Wout[(size_t)tg * H_ + d];
    #pragma unroll
    for (int off = 32; off; off >>= 1) sum += __shfl_xor(sum, off);
    if (lane == 0) out[b * TAGS_ + tg] = sum + bout[tg];
}

// ---------------- host ----------------

extern "C" void kernel_launch(void* const* d_in, const int* in_sizes, int n_in,
                              void* d_out, int out_size, void* d_ws, size_t ws_size,
                              hipStream_t stream)
{
    const int*   x    = (const int*)  d_in[0];
    const float* emb  = (const float*)d_in[1];
    const float* Wih0 = (const float*)d_in[2];
    const float* Whh0 = (const float*)d_in[3];
    const float* bih0 = (const float*)d_in[4];
    const float* bhh0 = (const float*)d_in[5];
    const float* Wih1 = (const float*)d_in[6];
    const float* Whh1 = (const float*)d_in[7];
    const float* bih1 = (const float*)d_in[8];
    const float* bhh1 = (const float*)d_in[9];
    const float* Wout = (const float*)d_in[10];
    const float* bout = (const float*)d_in[11];
    float* out = (float*)d_out;

    char* p = (char*)d_ws;
    bf16* E    = (bf16*)p;  p += (size_t)T_ * B_ * H_ * 2;      // 32 MB
    bf16* Wp   = (bf16*)p;  p += (size_t)2 * 32 * 65536 * 2;    // 8 MB packed weights
    float* bias0 = (float*)p; p += (size_t)G_ * 4;
    float* bias1 = (float*)p; p += (size_t)G_ * 4;
    char* zbase = p;                                            // zeroed every launch
    bf16* h0ring = (bf16*)p; p += (size_t)8 * B_ * H_ * 2;      // 512 KB
    bf16* h1ring = (bf16*)p; p += (size_t)8 * B_ * H_ * 2;      // 512 KB
    int*  flags  = (int*)p;  p += 8 * 32 * 4;                   // per-strip progress
    size_t zbytes = (size_t)(p - zbase);
    float* last1 = (float*)p; p += (size_t)B_ * H_ * 4;
    int* lens = (int*)p; p += 256;

    (void)hipFuncSetAttribute((const void*)k_lstm,
                              hipFuncAttributeMaxDynamicSharedMemorySize, 136192);

    k_zero<<<dim3(128), dim3(256), 0, stream>>>((uint32_t*)zbase, (int)(zbytes / 4));
    k_lens<<<dim3(B_), dim3(256), 0, stream>>>(x, lens);
    k_addb<<<dim3(8), dim3(256), 0, stream>>>(bih0, bhh0, bias0, G_);
    k_addb<<<dim3(8), dim3(256), 0, stream>>>(bih1, bhh1, bias1, G_);
    k_pack<<<dim3(32, 4, 2), dim3(256), 0, stream>>>(Wih0, Whh0, Wih1, Whh1, Wp);
    k_gather<<<dim3(T_, B_), dim3(256), 0, stream>>>(x, emb, E);

    k_lstm<<<dim3(256), dim3(256), 136192, stream>>>(Wp, E, bias0, bias1,
                                                     h0ring, h1ring, flags, last1, lens);

    k_out<<<dim3(B_, TAGS_), dim3(64), 0, stream>>>(last1, Wout, bout, out);
}

// Round 6
// 3072.206 us; speedup vs baseline: 2.0094x; 1.0748x over previous
//
#include <hip/hip_runtime.h>
#include <hip/hip_bf16.h>
#include <stdint.h>

#define B_    64
#define T_    512
#define H_    512
#define G_    2048    // 4*H
#define TAGS_ 20

typedef __hip_bfloat16 bf16;
typedef __bf16 bf16x8 __attribute__((ext_vector_type(8)));
typedef float  f32x4  __attribute__((ext_vector_type(4)));

__device__ __forceinline__ float sigmoidf_(float x) { return 1.0f / (1.0f + __expf(-x)); }

// ---------------- prep kernels ----------------

__global__ void k_zero(uint32_t* __restrict__ p, int n) {
    for (int i = blockIdx.x * blockDim.x + threadIdx.x; i < n; i += gridDim.x * blockDim.x)
        p[i] = 0u;
}

__global__ void k_addb(const float* __restrict__ a, const float* __restrict__ b,
                       float* __restrict__ o, int n) {
    for (int i = blockIdx.x * blockDim.x + threadIdx.x; i < n; i += gridDim.x * blockDim.x)
        o[i] = a[i] + b[i];
}

__global__ __launch_bounds__(256) void k_lens(const int* __restrict__ x, int* __restrict__ lens) {
    int b = blockIdx.x;
    int cnt = 0;
    for (int tpos = threadIdx.x; tpos < T_; tpos += 256)
        cnt += (x[(size_t)b * T_ + tpos] == 0) ? 1 : 0;
    #pragma unroll
    for (int off = 32; off; off >>= 1) cnt += __shfl_xor(cnt, off);
    __shared__ int tot;
    if (threadIdx.x == 0) tot = 0;
    __syncthreads();
    if ((threadIdx.x & 63) == 0) atomicAdd(&tot, cnt);
    __syncthreads();
    if (threadIdx.x == 0) lens[b] = T_ - tot;
}

// E[t][b][d] = bf16(emb[x[b][t]][d])
__global__ void k_gather(const int* __restrict__ x, const float* __restrict__ emb,
                         bf16* __restrict__ E) {
    int t = blockIdx.x, b = blockIdx.y;
    int tok = x[(size_t)b * T_ + t];
    const float* src = emb + (size_t)tok * H_;
    bf16* dst = E + ((size_t)t * B_ + b) * H_;
    for (int d = threadIdx.x; d < H_; d += blockDim.x)
        dst[d] = __float2bfloat16(src[d]);
}

// Pack weights into fragment-linear order (fused fp32->bf16)
__global__ __launch_bounds__(256) void k_pack(const float* __restrict__ Wih0, const float* __restrict__ Whh0,
                                              const float* __restrict__ Wih1, const float* __restrict__ Whh1,
                                              bf16* __restrict__ Wp) {
    const int s = blockIdx.x, q = blockIdx.y, l = blockIdx.z;
    const float* Wx = l ? Wih1 : Wih0;
    const float* Wh = l ? Whh1 : Whh0;
    bf16* base = Wp + (size_t)(l * 32 + s) * 65536;
    for (int u = threadIdx.x; u < 2048; u += 256) {
        int kc = u >> 6, lane = u & 63;
        int row = q * H_ + s * 16 + (lane & 15);
        int col = (kc & 15) * 32 + (lane >> 4) * 8;
        const float* src = ((kc < 16) ? Wx : Wh) + (size_t)row * H_ + col;
        bf16* dst = base + ((size_t)(q * 32 + kc) * 64 + lane) * 8;
        #pragma unroll
        for (int e = 0; e < 8; ++e) dst[e] = __float2bfloat16(src[e]);
    }
}

// ---------------- sync helpers (all L3-coherent: sc0 sc1) ----------------

// Always ends with vmcnt(0)+sched_barrier(0): any previously issued async
// loads (flags, data) are valid after return, and no builtin can hoist above.
__device__ __forceinline__ void poll_flags(const int* arr, int thr, int lane) {
    if (thr > 0) {
        const int* p = arr + (lane & 31);
        int gd = 0;
        while (true) {
            int v;
            asm volatile("global_load_dword %0, %1, off sc0 sc1\n\ts_waitcnt vmcnt(0)"
                         : "=v"(v) : "v"(p) : "memory");
            if (__all(v >= thr)) break;
            if (++gd > (1 << 16)) break;    // bounded worst case, no 600s hang
            __builtin_amdgcn_s_sleep(1);
        }
    }
    asm volatile("s_waitcnt vmcnt(0)" ::: "memory");
    __builtin_amdgcn_sched_barrier(0);
}

#define ISSUE16(arr, base, SC)                                               \
    _Pragma("unroll")                                                        \
    for (int kc = 0; kc < 16; ++kc) {                                        \
        asm volatile("global_load_dwordx4 %0, %1, off" SC                    \
                     : "=v"(arr[kc]) : "v"((base) + kc * 32));               \
    }

#define WAITALL()                                                            \
    asm volatile("s_waitcnt vmcnt(0)" ::: "memory");                         \
    __builtin_amdgcn_sched_barrier(0);

#define MFMA16(arr, woff)                                                    \
    _Pragma("unroll")                                                        \
    for (int kc = 0; kc < 16; ++kc) {                                        \
        f32x4 wf = wldsv[(size_t)(q * 32 + (woff) + kc) * 64 + lane];        \
        acc[kc & 3] = __builtin_amdgcn_mfma_f32_16x16x32_bf16(               \
            __builtin_bit_cast(bf16x8, arr[kc]),                             \
            __builtin_bit_cast(bf16x8, wf), acc[kc & 3], 0, 0, 0);           \
    }

// ---------------- persistent 2-layer LSTM ----------------
// 256 blocks (1/CU, 133KB dyn LDS). block = (g=bid&7 -> (layer,m), strip s=bid>>3).
// Weights in LDS (fragment-linear). c in registers. All cross-block traffic is
// L3-coherent (sc0 sc1) — round-3-proven protocol; latency overlapped via
// speculative flag loads and load/compute interleave.
__global__ __launch_bounds__(256, 1) void k_lstm(
    const bf16* __restrict__ Wp, const bf16* __restrict__ E,
    const float* __restrict__ bias0, const float* __restrict__ bias1,
    bf16* __restrict__ h0ring, bf16* __restrict__ h1ring,
    int* __restrict__ fx, float* __restrict__ last1, const int* __restrict__ lens)
{
    extern __shared__ char smem[];                       // [0,128K) weights, [128K,+5K) gates
    f32x4* wldsv = (f32x4*)smem;
    float (*glds)[16][20] = (float (*)[16][20])(smem + 131072);

    const int bid   = blockIdx.x;
    const int g     = bid & 7;           // group: layer*4+m
    const int s     = bid >> 3;          // strip 0..31
    const int layer = g >> 2;
    const int m     = g & 3;
    const int tid   = threadIdx.x;
    const int lane  = tid & 63;
    const int q     = tid >> 6;          // wave = gate
    const int kq    = (lane >> 4) * 8;
    const int arow  = m * 16 + (lane & 15);

    // ---- stage this block's 128KB weight slice into LDS ----
    {
        const f32x4* wsrc = (const f32x4*)(Wp + (size_t)(layer * 32 + s) * 65536);
        for (int i = tid; i < 8192; i += 256) wldsv[i] = wsrc[i];
    }

    // ---- elementwise mapping: one (b,j) per thread, c in register ----
    const int eb   = tid >> 4;
    const int ej   = tid & 15;
    const int brow = m * 16 + eb;
    const int jcol = s * 16 + ej;
    float c_reg = 0.f;
    const float* bias = layer ? bias1 : bias0;
    const float bi0 = bias[0 * H_ + jcol];
    const float bi1 = bias[1 * H_ + jcol];
    const float bi2 = bias[2 * H_ + jcol];
    const float bi3 = bias[3 * H_ + jcol];
    int target = lens[brow] - 1;
    if (target < 0) target = T_ - 1;

    int*       fown  = fx + g * 32;            // own group progress
    const int* fx_l1 = fx + (4 + m) * 32;      // layer-1 group m progress
    const int* fx_l0 = fx + m * 32;            // layer-0 group m progress

    bf16* myring = layer ? h1ring : h0ring;
    const int rb = (lane >> 4) * 4;
    const int l15 = lane & 15;

    __syncthreads();                           // weights staged

    for (int tt = 0; tt < T_; ++tt) {
        f32x4 acc[4];
        #pragma unroll
        for (int i = 0; i < 4; ++i) acc[i] = f32x4{0.f, 0.f, 0.f, 0.f};
        f32x4 ax[16], ah[16];
        const size_t slot_w = (size_t)(tt & 7) * (B_ * H_);
        const size_t slot_r = (size_t)((tt - 1) & 7) * (B_ * H_);
        int fv;

        if (layer == 0) {
            // async cross-layer flag (ring flow control), checked after poll
            asm volatile("global_load_dword %0, %1, off sc0 sc1"
                         : "=v"(fv) : "v"(fx_l1 + (lane & 31)) : "memory");
            // E x-loads: no dependency; latency hides under the poll
            const bf16* xp = E + ((size_t)tt * B_ + arow) * H_ + kq;
            ISSUE16(ax, xp, "")
            poll_flags(fown, tt, lane);              // ends vmcnt(0): ax, fv valid
            if (tt >= 8 && !__all(fv >= tt - 7)) poll_flags(fx_l1, tt - 7, lane);
            const bf16* hp = h0ring + slot_r + (size_t)arow * H_ + kq;
            ISSUE16(ah, hp, " sc0 sc1")
            MFMA16(ax, 0)                            // x-compute hides h RT
            WAITALL()
            MFMA16(ah, 16)
        } else {
            // async l0-progress flag, checked after own poll
            asm volatile("global_load_dword %0, %1, off sc0 sc1"
                         : "=v"(fv) : "v"(fx_l0 + (lane & 31)) : "memory");
            poll_flags(fown, tt, lane);              // ends vmcnt(0): fv valid
            const bf16* hp = h1ring + slot_r + (size_t)arow * H_ + kq;
            ISSUE16(ah, hp, " sc0 sc1")
            if (!__all(fv >= tt + 1)) poll_flags(fx_l0, tt + 1, lane);
            const bf16* xp = h0ring + slot_w + (size_t)arow * H_ + kq;
            ISSUE16(ax, xp, " sc0 sc1")              // both data RTs overlap
            WAITALL()
            MFMA16(ax, 0)
            MFMA16(ah, 16)
        }

        f32x4 gsum = (acc[0] + acc[1]) + (acc[2] + acc[3]);

        // ---- gate exchange via LDS ----
        *reinterpret_cast<f32x4*>(&glds[q][l15][rb]) = gsum;
        __syncthreads();

        // ---- elementwise LSTM update ----
        float gi = sigmoidf_(glds[0][ej][eb] + bi0);
        float gf = sigmoidf_(glds[1][ej][eb] + bi1);
        float gg = tanhf   (glds[2][ej][eb] + bi2);
        float go = sigmoidf_(glds[3][ej][eb] + bi3);
        c_reg = gf * c_reg + gi * gg;
        float hn = go * tanhf(c_reg);

        {
            bf16 hb = __float2bfloat16(hn);
            uint32_t hv = (uint32_t)__builtin_bit_cast(unsigned short, hb);
            bf16* hw = myring + slot_w + (size_t)brow * H_ + jcol;
            asm volatile("global_store_short %0, %1, off sc0 sc1" :: "v"(hw), "v"(hv) : "memory");
        }
        if (layer == 1 && tt == target)
            last1[(size_t)brow * H_ + jcol] = hn;

        asm volatile("s_waitcnt vmcnt(0)" ::: "memory");   // own stores at L3
        __syncthreads();                                   // all threads drained (+glds reads done)
        if (tid == 0) {
            int fv2 = tt + 1;
            int* fp = fown + s;
            asm volatile("global_store_dword %0, %1, off sc0 sc1" :: "v"(fp), "v"(fv2) : "memory");
        }
        // no trailing barrier: next glds write is separated by the drain barrier above
    }
}

// out[b][tag] = last1[b] . Wout[tag] + bout[tag]   (fp32)
__global__ __launch_bounds__(64) void k_out(const float* __restrict__ last1,
                                            const float* __restrict__ Wout,
                                            const float* __restrict__ bout,
                                            float* __restrict__ out) {
    int b = blockIdx.x, tg = blockIdx.y, lane = threadIdx.x;
    float sum = 0.f;
    for (int d = lane; d < H_; d += 64)
        sum += last1[(size_t)b * H_ + d] * Wout[(size_t)tg * H_ + d];
    #pragma unroll
    for (int off = 32; off; off >>= 1) sum += __shfl_xor(sum, off);
    if (lane == 0) out[b * TAGS_ + tg] = sum + bout[tg];
}

// ---------------- host ----------------

extern "C" void kernel_launch(void* const* d_in, const int* in_sizes, int n_in,
                              void* d_out, int out_size, void* d_ws, size_t ws_size,
                              hipStream_t stream)
{
    const int*   x    = (const int*)  d_in[0];
    const float* emb  = (const float*)d_in[1];
    const float* Wih0 = (const float*)d_in[2];
    const float* Whh0 = (const float*)d_in[3];
    const float* bih0 = (const float*)d_in[4];
    const float* bhh0 = (const float*)d_in[5];
    const float* Wih1 = (const float*)d_in[6];
    const float* Whh1 = (const float*)d_in[7];
    const float* bih1 = (const float*)d_in[8];
    const float* bhh1 = (const float*)d_in[9];
    const float* Wout = (const float*)d_in[10];
    const float* bout = (const float*)d_in[11];
    float* out = (float*)d_out;

    char* p = (char*)d_ws;
    bf16* E    = (bf16*)p;  p += (size_t)T_ * B_ * H_ * 2;      // 32 MB
    bf16* Wp   = (bf16*)p;  p += (size_t)2 * 32 * 65536 * 2;    // 8 MB packed weights
    float* bias0 = (float*)p; p += (size_t)G_ * 4;
    float* bias1 = (float*)p; p += (size_t)G_ * 4;
    char* zbase = p;                                            // zeroed every launch
    bf16* h0ring = (bf16*)p; p += (size_t)8 * B_ * H_ * 2;      // 512 KB
    bf16* h1ring = (bf16*)p; p += (size_t)8 * B_ * H_ * 2;      // 512 KB
    int*  fx     = (int*)p;  p += 8 * 32 * 4;                   // per-strip progress flags
    size_t zbytes = (size_t)(p - zbase);
    float* last1 = (float*)p; p += (size_t)B_ * H_ * 4;
    int* lens = (int*)p; p += 256;

    (void)hipFuncSetAttribute((const void*)k_lstm,
                              hipFuncAttributeMaxDynamicSharedMemorySize, 136192);

    k_zero<<<dim3(128), dim3(256), 0, stream>>>((uint32_t*)zbase, (int)(zbytes / 4));
    k_lens<<<dim3(B_), dim3(256), 0, stream>>>(x, lens);
    k_addb<<<dim3(8), dim3(256), 0, stream>>>(bih0, bhh0, bias0, G_);
    k_addb<<<dim3(8), dim3(256), 0, stream>>>(bih1, bhh1, bias1, G_);
    k_pack<<<dim3(32, 4, 2), dim3(256), 0, stream>>>(Wih0, Whh0, Wih1, Whh1, Wp);
    k_gather<<<dim3(T_, B_), dim3(256), 0, stream>>>(x, emb, E);

    k_lstm<<<dim3(256), dim3(256), 136192, stream>>>(Wp, E, bias0, bias1,
                                                     h0ring, h1ring, fx, last1, lens);

    k_out<<<dim3(B_, TAGS_), dim3(64), 0, stream>>>(last1, Wout, bout, out);
}

// Round 7
// 3001.962 us; speedup vs baseline: 2.0564x; 1.0234x over previous
//
#include <hip/hip_runtime.h>
#include <hip/hip_bf16.h>
#include <stdint.h>

#define B_    64
#define T_    512
#define H_    512
#define G_    2048    // 4*H
#define TAGS_ 20

typedef __hip_bfloat16 bf16;
typedef __bf16 bf16x8 __attribute__((ext_vector_type(8)));
typedef float  f32x4  __attribute__((ext_vector_type(4)));

__device__ __forceinline__ float sigmoidf_(float x) { return 1.0f / (1.0f + __expf(-x)); }

// ---------------- prep kernels ----------------

__global__ void k_zero(uint32_t* __restrict__ p, int n) {
    for (int i = blockIdx.x * blockDim.x + threadIdx.x; i < n; i += gridDim.x * blockDim.x)
        p[i] = 0u;
}

__global__ void k_addb(const float* __restrict__ a, const float* __restrict__ b,
                       float* __restrict__ o, int n) {
    for (int i = blockIdx.x * blockDim.x + threadIdx.x; i < n; i += gridDim.x * blockDim.x)
        o[i] = a[i] + b[i];
}

__global__ __launch_bounds__(256) void k_lens(const int* __restrict__ x, int* __restrict__ lens) {
    int b = blockIdx.x;
    int cnt = 0;
    for (int tpos = threadIdx.x; tpos < T_; tpos += 256)
        cnt += (x[(size_t)b * T_ + tpos] == 0) ? 1 : 0;
    #pragma unroll
    for (int off = 32; off; off >>= 1) cnt += __shfl_xor(cnt, off);
    __shared__ int tot;
    if (threadIdx.x == 0) tot = 0;
    __syncthreads();
    if ((threadIdx.x & 63) == 0) atomicAdd(&tot, cnt);
    __syncthreads();
    if (threadIdx.x == 0) lens[b] = T_ - tot;
}

// E[t][b][d] = bf16(emb[x[b][t]][d])
__global__ void k_gather(const int* __restrict__ x, const float* __restrict__ emb,
                         bf16* __restrict__ E) {
    int t = blockIdx.x, b = blockIdx.y;
    int tok = x[(size_t)b * T_ + t];
    const float* src = emb + (size_t)tok * H_;
    bf16* dst = E + ((size_t)t * B_ + b) * H_;
    for (int d = threadIdx.x; d < H_; d += blockDim.x)
        dst[d] = __float2bfloat16(src[d]);
}

// Pack weights into fragment-linear order (fused fp32->bf16)
__global__ __launch_bounds__(256) void k_pack(const float* __restrict__ Wih0, const float* __restrict__ Whh0,
                                              const float* __restrict__ Wih1, const float* __restrict__ Whh1,
                                              bf16* __restrict__ Wp) {
    const int s = blockIdx.x, q = blockIdx.y, l = blockIdx.z;
    const float* Wx = l ? Wih1 : Wih0;
    const float* Wh = l ? Whh1 : Whh0;
    bf16* base = Wp + (size_t)(l * 32 + s) * 65536;
    for (int u = threadIdx.x; u < 2048; u += 256) {
        int kc = u >> 6, lane = u & 63;
        int row = q * H_ + s * 16 + (lane & 15);
        int col = (kc & 15) * 32 + (lane >> 4) * 8;
        const float* src = ((kc < 16) ? Wx : Wh) + (size_t)row * H_ + col;
        bf16* dst = base + ((size_t)(q * 32 + kc) * 64 + lane) * 8;
        #pragma unroll
        for (int e = 0; e < 8; ++e) dst[e] = __float2bfloat16(src[e]);
    }
}

// ---------------- sync helpers ----------------
// Counters: one dword per group (own 128B line). Proven primitives (round 1):
// RELAXED+AGENT atomic load/add — device-coherent, no cache-wide fences.

__device__ __forceinline__ void poll_ctr(const int* ctr, int thr) {
    if (thr > 0) {
        int gd = 0;
        while (__hip_atomic_load(ctr, __ATOMIC_RELAXED, __HIP_MEMORY_SCOPE_AGENT) < thr) {
            if (++gd > (1 << 18)) break;       // bounded worst case
            __builtin_amdgcn_s_sleep(2);       // ~128cy backoff: low poll rate
        }
    }
    __builtin_amdgcn_sched_barrier(0);
}

#define ISSUE16(arr, base, SC)                                               \
    _Pragma("unroll")                                                        \
    for (int kc = 0; kc < 16; ++kc) {                                        \
        asm volatile("global_load_dwordx4 %0, %1, off" SC                    \
                     : "=v"(arr[kc]) : "v"((base) + kc * 32));               \
    }

#define WAITALL()                                                            \
    asm volatile("s_waitcnt vmcnt(0)" ::: "memory");                         \
    __builtin_amdgcn_sched_barrier(0);

#define MFMA16(arr, woff)                                                    \
    _Pragma("unroll")                                                        \
    for (int kc = 0; kc < 16; ++kc) {                                        \
        f32x4 wf = wldsv[(size_t)(q * 32 + (woff) + kc) * 64 + lane];        \
        acc[kc & 3] = __builtin_amdgcn_mfma_f32_16x16x32_bf16(               \
            __builtin_bit_cast(bf16x8, arr[kc]),                             \
            __builtin_bit_cast(bf16x8, wf), acc[kc & 3], 0, 0, 0);           \
    }

// ---------------- persistent 2-layer LSTM ----------------
// 256 blocks (1/CU, 133KB dyn LDS). block = (g=bid&7 -> (layer,m), strip s=bid>>3).
// Weights in LDS (fragment-linear). c in registers. Cross-block data via sc0 sc1
// (L3-coherent, proven). Sync via ONE atomic counter per group: publish=atomicAdd,
// wait=broadcast poll of a single dword with backoff (no flag-array request storm).
__global__ __launch_bounds__(256, 1) void k_lstm(
    const bf16* __restrict__ Wp, const bf16* __restrict__ E,
    const float* __restrict__ bias0, const float* __restrict__ bias1,
    bf16* __restrict__ h0ring, bf16* __restrict__ h1ring,
    int* __restrict__ ctrs, float* __restrict__ last1, const int* __restrict__ lens)
{
    extern __shared__ char smem[];                       // [0,128K) weights, [128K,+5K) gates
    f32x4* wldsv = (f32x4*)smem;
    float (*glds)[16][20] = (float (*)[16][20])(smem + 131072);

    const int bid   = blockIdx.x;
    const int g     = bid & 7;           // group: layer*4+m
    const int s     = bid >> 3;          // strip 0..31
    const int layer = g >> 2;
    const int m     = g & 3;
    const int tid   = threadIdx.x;
    const int lane  = tid & 63;
    const int q     = tid >> 6;          // wave = gate
    const int kq    = (lane >> 4) * 8;
    const int arow  = m * 16 + (lane & 15);

    // ---- stage this block's 128KB weight slice into LDS ----
    {
        const f32x4* wsrc = (const f32x4*)(Wp + (size_t)(layer * 32 + s) * 65536);
        for (int i = tid; i < 8192; i += 256) wldsv[i] = wsrc[i];
    }

    // ---- elementwise mapping: one (b,j) per thread, c in register ----
    const int eb   = tid >> 4;
    const int ej   = tid & 15;
    const int brow = m * 16 + eb;
    const int jcol = s * 16 + ej;
    float c_reg = 0.f;
    const float* bias = layer ? bias1 : bias0;
    const float bi0 = bias[0 * H_ + jcol];
    const float bi1 = bias[1 * H_ + jcol];
    const float bi2 = bias[2 * H_ + jcol];
    const float bi3 = bias[3 * H_ + jcol];
    int target = lens[brow] - 1;
    if (target < 0) target = T_ - 1;

    int* ctr_own = ctrs + g * 32;              // own group's counter (128B apart)
    int* ctr_oth = ctrs + (g ^ 4) * 32;        // other layer, same m

    bf16* myring = layer ? h1ring : h0ring;
    const int rb = (lane >> 4) * 4;
    const int l15 = lane & 15;

    __syncthreads();                           // weights staged

    for (int tt = 0; tt < T_; ++tt) {
        f32x4 acc[4];
        #pragma unroll
        for (int i = 0; i < 4; ++i) acc[i] = f32x4{0.f, 0.f, 0.f, 0.f};
        f32x4 ax[16], ah[16];
        const size_t slot_w = (size_t)(tt & 7) * (B_ * H_);
        const size_t slot_r = (size_t)((tt - 1) & 7) * (B_ * H_);

        if (layer == 0) {
            // speculative ring-flow check (l1 progress), resolved in-register
            int spec = (tt >= 8)
                ? __hip_atomic_load(ctr_oth, __ATOMIC_RELAXED, __HIP_MEMORY_SCOPE_AGENT)
                : 0x7fffffff;
            // x-part from E: zero dependencies — fully before the sync
            const bf16* xp = E + ((size_t)tt * B_ + arow) * H_ + kq;
            ISSUE16(ax, xp, "")
            WAITALL()
            MFMA16(ax, 0)
            poll_ctr(ctr_own, 32 * tt);                       // group done step tt-1
            if (tt >= 8 && spec < 32 * (tt - 7)) poll_ctr(ctr_oth, 32 * (tt - 7));
            const bf16* hp = h0ring + slot_r + (size_t)arow * H_ + kq;
            ISSUE16(ah, hp, " sc0 sc1")
            WAITALL()
            MFMA16(ah, 16)
        } else {
            // speculative l0-progress check, resolved after own poll
            int spec = __hip_atomic_load(ctr_oth, __ATOMIC_RELAXED, __HIP_MEMORY_SCOPE_AGENT);
            poll_ctr(ctr_own, 32 * tt);                       // group done step tt-1
            const bf16* hp = h1ring + slot_r + (size_t)arow * H_ + kq;
            ISSUE16(ah, hp, " sc0 sc1")
            if (spec < 32 * (tt + 1)) poll_ctr(ctr_oth, 32 * (tt + 1));  // l0 done step tt
            const bf16* xp = h0ring + slot_w + (size_t)arow * H_ + kq;
            ISSUE16(ax, xp, " sc0 sc1")
            WAITALL()                                          // both data RTs overlap
            MFMA16(ax, 0)
            MFMA16(ah, 16)
        }

        f32x4 gsum = (acc[0] + acc[1]) + (acc[2] + acc[3]);

        // ---- gate exchange via LDS ----
        *reinterpret_cast<f32x4*>(&glds[q][l15][rb]) = gsum;
        __syncthreads();

        // ---- elementwise LSTM update ----
        float gi = sigmoidf_(glds[0][ej][eb] + bi0);
        float gf = sigmoidf_(glds[1][ej][eb] + bi1);
        float gg = tanhf   (glds[2][ej][eb] + bi2);
        float go = sigmoidf_(glds[3][ej][eb] + bi3);
        c_reg = gf * c_reg + gi * gg;
        float hn = go * tanhf(c_reg);

        {
            bf16 hb = __float2bfloat16(hn);
            uint32_t hv = (uint32_t)__builtin_bit_cast(unsigned short, hb);
            bf16* hw = myring + slot_w + (size_t)brow * H_ + jcol;
            asm volatile("global_store_short %0, %1, off sc0 sc1" :: "v"(hw), "v"(hv) : "memory");
        }
        if (layer == 1 && tt == target)
            last1[(size_t)brow * H_ + jcol] = hn;

        asm volatile("s_waitcnt vmcnt(0)" ::: "memory");   // h at L3 before publish
        __syncthreads();                                   // whole block drained
        if (tid == 0)
            __hip_atomic_fetch_add(ctr_own, 1, __ATOMIC_RELAXED, __HIP_MEMORY_SCOPE_AGENT);
    }
}

// out[b][tag] = last1[b] . Wout[tag] + bout[tag]   (fp32)
__global__ __launch_bounds__(64) void k_out(const float* __restrict__ last1,
                                            const float* __restrict__ Wout,
                                            const float* __restrict__ bout,
                                            float* __restrict__ out) {
    int b = blockIdx.x, tg = blockIdx.y, lane = threadIdx.x;
    float sum = 0.f;
    for (int d = lane; d < H_; d += 64)
        sum += last1[(size_t)b * H_ + d] * Wout[(size_t)tg * H_ + d];
    #pragma unroll
    for (int off = 32; off; off >>= 1) sum += __shfl_xor(sum, off);
    if (lane == 0) out[b * TAGS_ + tg] = sum + bout[tg];
}

// ---------------- host ----------------

extern "C" void kernel_launch(void* const* d_in, const int* in_sizes, int n_in,
                              void* d_out, int out_size, void* d_ws, size_t ws_size,
                              hipStream_t stream)
{
    const int*   x    = (const int*)  d_in[0];
    const float* emb  = (const float*)d_in[1];
    const float* Wih0 = (const float*)d_in[2];
    const float* Whh0 = (const float*)d_in[3];
    const float* bih0 = (const float*)d_in[4];
    const float* bhh0 = (const float*)d_in[5];
    const float* Wih1 = (const float*)d_in[6];
    const float* Whh1 = (const float*)d_in[7];
    const float* bih1 = (const float*)d_in[8];
    const float* bhh1 = (const float*)d_in[9];
    const float* Wout = (const float*)d_in[10];
    const float* bout = (const float*)d_in[11];
    float* out = (float*)d_out;

    char* p = (char*)d_ws;
    bf16* E    = (bf16*)p;  p += (size_t)T_ * B_ * H_ * 2;      // 32 MB
    bf16* Wp   = (bf16*)p;  p += (size_t)2 * 32 * 65536 * 2;    // 8 MB packed weights
    float* bias0 = (float*)p; p += (size_t)G_ * 4;
    float* bias1 = (float*)p; p += (size_t)G_ * 4;
    char* zbase = p;                                            // zeroed every launch
    bf16* h0ring = (bf16*)p; p += (size_t)8 * B_ * H_ * 2;      // 512 KB
    bf16* h1ring = (bf16*)p; p += (size_t)8 * B_ * H_ * 2;      // 512 KB
    int*  ctrs   = (int*)p;  p += 8 * 32 * 4;                   // 8 group counters, 128B apart
    size_t zbytes = (size_t)(p - zbase);
    float* last1 = (float*)p; p += (size_t)B_ * H_ * 4;
    int* lens = (int*)p; p += 256;

    (void)hipFuncSetAttribute((const void*)k_lstm,
                              hipFuncAttributeMaxDynamicSharedMemorySize, 136192);

    k_zero<<<dim3(128), dim3(256), 0, stream>>>((uint32_t*)zbase, (int)(zbytes / 4));
    k_lens<<<dim3(B_), dim3(256), 0, stream>>>(x, lens);
    k_addb<<<dim3(8), dim3(256), 0, stream>>>(bih0, bhh0, bias0, G_);
    k_addb<<<dim3(8), dim3(256), 0, stream>>>(bih1, bhh1, bias1, G_);
    k_pack<<<dim3(32, 4, 2), dim3(256), 0, stream>>>(Wih0, Whh0, Wih1, Whh1, Wp);
    k_gather<<<dim3(T_, B_), dim3(256), 0, stream>>>(x, emb, E);

    k_lstm<<<dim3(256), dim3(256), 136192, stream>>>(Wp, E, bias0, bias1,
                                                     h0ring, h1ring, ctrs, last1, lens);

    k_out<<<dim3(B_, TAGS_), dim3(64), 0, stream>>>(last1, Wout, bout, out);
}